// Round 9
// baseline (877.858 us; speedup 1.0000x reference)
//
#include <hip/hip_runtime.h>
#include <hip/hip_cooperative_groups.h>
#include <cstdint>
#include <cstddef>

namespace cg = cooperative_groups;

#define M_DIM 2048
#define N_DIM 4096
#define K_DIM 20000
#define KP    20480                 /* K padded to multiple of 64 (zero-filled) */
#define KZ    10240                 /* K per split-K plane (2 planes) */
#define NTILE 160                   /* KZ / 64 K-tiles per plane */
#define WBT_BYTES  167772160UL      /* 4096*20480*2 : bf16 W^T (N x KP) */
#define XB_OFFSET  167772160UL      /* bf16 x (M x KP) after Wbt */
#define CP_OFFSET  251658240UL      /* 2x fp32 C-partials after xb */
#define PREP_T 262144               /* 1024 blocks x 256 threads */

typedef __attribute__((ext_vector_type(8))) short short8;
typedef __attribute__((ext_vector_type(2))) short short2v;
typedef __attribute__((ext_vector_type(4))) float float4v;
typedef __attribute__((ext_vector_type(8))) unsigned short ushort8;

__device__ __forceinline__ unsigned short f2bf_rne(float f) {
    union { float f; unsigned int u; } v; v.f = f;
    unsigned int u = v.u;
    u += 0x7FFFu + ((u >> 16) & 1u);   // round-to-nearest-even
    return (unsigned short)(u >> 16);
}

__device__ __forceinline__ float bf2f(unsigned short h) {
    union { unsigned int u; float f; } v;
    v.u = ((unsigned int)h) << 16;
    return v.f;
}

__device__ __forceinline__ void gload_lds16(const void* g, void* l) {
    __builtin_amdgcn_global_load_lds(
        (const __attribute__((address_space(1))) void*)g,
        (__attribute__((address_space(3))) void*)l, 16, 0, 0);
}

// ---- 1. cooperative prep: zero Wbt -> grid.sync -> scatter + convert ----
// 1024 blocks x 256 thr, co-resident (4 wg/CU, no LDS, low VGPR).
// Phase A: zero 168 MB Wbt (40 float4/thread, exact cover).
// grid.sync (device-scope visibility for the scatter's memory-side atomics).
// Phase B: scatter 2M packed-bf16 atomics (fire-and-forget, <=8/thread),
// then Phase C: x fp32->bf16 convert (20 ushort8 slots/thread, exact cover)
// streams while the atomic RMWs drain in the cache hierarchy.
__global__ void prep_kernel(const float* __restrict__ x,
                            unsigned short* __restrict__ xb,
                            float4* __restrict__ wz,
                            const float* __restrict__ kv,
                            const int* __restrict__ ind,
                            unsigned int* __restrict__ W,
                            int nnz) {
    const size_t t = (size_t)blockIdx.x * 256 + threadIdx.x;

    // A: zero Wbt (incl. K-pad): 10485760 float4 = 40 * 262144
    float4 z; z.x = 0.f; z.y = 0.f; z.z = 0.f; z.w = 0.f;
    #pragma unroll
    for (int i = 0; i < 40; ++i)
        wz[t + (size_t)i * PREP_T] = z;

    __threadfence();
    cg::this_grid().sync();

    // B: scatter-add COO into bf16 W^T (N_DIM x KP row-major)
    #pragma unroll
    for (int i = 0; i < 8; ++i) {
        size_t idx = t + (size_t)i * PREP_T;
        if (idx < (size_t)nnz) {
            int r = ind[2 * idx];      // input_dim index (K)
            int c = ind[2 * idx + 1];  // units index (N)
            float v = kv[idx];
            size_t elem = (size_t)c * KP + r;
            unsigned int* word = &W[elem >> 1];
            const bool hi = (elem & 1) != 0;     // KP even: no straddle
            unsigned short hbits = f2bf_rne(v);
#if __has_builtin(__builtin_amdgcn_global_atomic_fadd_v2bf16)
            short2v val;
            val[0] = hi ? (short)0 : (short)hbits;
            val[1] = hi ? (short)hbits : (short)0;
            __builtin_amdgcn_global_atomic_fadd_v2bf16(
                (__attribute__((address_space(1))) short2v*)word, val);
#else
            unsigned int expected = 0u;
            unsigned int desired  = hi ? ((unsigned int)hbits << 16)
                                       : (unsigned int)hbits;
            for (;;) {
                unsigned int old = atomicCAS(word, expected, desired);
                if (old == expected) break;
                expected = old;
                unsigned short hcur = hi ? (unsigned short)(old >> 16)
                                         : (unsigned short)(old & 0xFFFFu);
                unsigned short nh = f2bf_rne(bf2f(hcur) + v);
                desired = hi ? ((old & 0x0000FFFFu) | ((unsigned int)nh << 16))
                             : ((old & 0xFFFF0000u) | (unsigned int)nh);
            }
#endif
        }
    }

    // C: convert x fp32 -> bf16, padded rows (2560 slots/row, 2500 real);
    // 5242880 slots = 20 * 262144. Overlaps the atomic drain.
    #pragma unroll
    for (int i = 0; i < 20; ++i) {
        size_t s = t + (size_t)i * PREP_T;
        int row = (int)(s / 2560);
        int c8  = (int)(s % 2560);
        ushort8 o;
        if (c8 < 2500) {
            const float4* sv = (const float4*)(x + (size_t)row * K_DIM + (size_t)c8 * 8);
            float4 a = sv[0];
            float4 b = sv[1];
            o[0] = f2bf_rne(a.x); o[1] = f2bf_rne(a.y);
            o[2] = f2bf_rne(a.z); o[3] = f2bf_rne(a.w);
            o[4] = f2bf_rne(b.x); o[5] = f2bf_rne(b.y);
            o[6] = f2bf_rne(b.z); o[7] = f2bf_rne(b.w);
        } else {
            o = (ushort8)0;
        }
        *(ushort8*)(xb + (size_t)row * KP + (size_t)c8 * 8) = o;
    }
}

// ---- 2. 256x256-tile split-K=2 GEMM, 4-phase/tile schedule, XOR-swizzled LDS ----
// (round-4/6 kernel, verbatim: 281 us, MfmaUtil 52%, 0 bank conflicts)
// Swizzle: 16B chunk c of row r stored at slot c^(r&7) -- HW-verified
// conflict-free for the 16-row x 4-quad fragment read pattern (16x16x32).
// Round-5 lesson: the 32x32x16 shape re-introduces conflicts; round-8 lesson:
// unbalanced phases (12 reads in P1) cost more than a fused epilogue saves.
__global__ __launch_bounds__(512, 2) void gemm256_kernel(
    const unsigned short* __restrict__ A,
    const unsigned short* __restrict__ Bt,
    float* __restrict__ Cp) {

    __shared__ unsigned short L[65536];    // 131072 B

    const int t    = threadIdx.x;
    const int w    = t >> 6;
    const int l    = t & 63;
    const int quad = l >> 4;
    const int r16  = l & 15;
    const int wm   = w >> 2;               // 0..1
    const int wn   = w & 3;                // 0..3

    const int m0 = blockIdx.y * 256;
    const int n0 = blockIdx.x * 256;
    const size_t k0 = (size_t)blockIdx.z * KZ;

    // staging lane mapping: row sub-index lr8 = l>>3, chunk sl = (l&7)^(l>>3)
    const int lr8 = l >> 3;
    const int sl  = (l & 7) ^ lr8;
    const int w1024 = w << 10;

    const unsigned short* pA0 = A  + (size_t)(m0 +   0 + w * 8 + lr8) * KP + k0 + sl * 8;
    const unsigned short* pA1 = A  + (size_t)(m0 +  64 + w * 8 + lr8) * KP + k0 + sl * 8;
    const unsigned short* pA2 = A  + (size_t)(m0 + 128 + w * 8 + lr8) * KP + k0 + sl * 8;
    const unsigned short* pA3 = A  + (size_t)(m0 + 192 + w * 8 + lr8) * KP + k0 + sl * 8;
    const unsigned short* pB0 = Bt + (size_t)(n0 +   0 + w * 8 + lr8) * KP + k0 + sl * 8;
    const unsigned short* pB1 = Bt + (size_t)(n0 +  64 + w * 8 + lr8) * KP + k0 + sl * 8;
    const unsigned short* pB2 = Bt + (size_t)(n0 + 128 + w * 8 + lr8) * KP + k0 + sl * 8;
    const unsigned short* pB3 = Bt + (size_t)(n0 + 192 + w * 8 + lr8) * KP + k0 + sl * 8;

    char* Lb = (char*)L;

    // buffer layout (byte offsets): buf b at b*65536; A slab [0,32K), B [32K,64K)
#define STG_A(OB, Q, P) do { \
    gload_lds16(P, Lb + (OB) + (Q) * 8192 + w1024); P += 64; } while (0)
#define STG_B(OB, Q, P) do { \
    gload_lds16(P, Lb + (OB) + 32768 + (Q) * 8192 + w1024); P += 64; } while (0)

    // read offsets: byte = row*128 + ((chunk)^(row&7))*16, chunk = kh*4+quad
    const int h   = r16 & 7;
    const int so0 = ((quad ^ h) << 4);          // kh = 0
    const int so1 = (((4 | quad) ^ h) << 4);    // kh = 1
    const int aoff = wm * 16384 + r16 * 128;    // + mh*8192 + i*2048
    const int boff = 32768 + wn * 8192 + r16 * 128;   // + j*2048

    float4v acc[8][4];
#pragma unroll
    for (int i = 0; i < 8; ++i)
#pragma unroll
        for (int j = 0; j < 4; ++j)
            acc[i][j] = (float4v){0.f, 0.f, 0.f, 0.f};

    short8 bfr[4], af[4];

#define VM2 asm volatile("s_waitcnt vmcnt(2)" ::: "memory")
#define VMNONE ((void)0)

#define PHASE(BUF, MH, SO, LOADB, STG, VM) do { \
    const char* base_ = Lb + (BUF); \
    if (LOADB) { \
        _Pragma("unroll") \
        for (int j = 0; j < 4; ++j) \
            bfr[j] = *(const short8*)(base_ + boff + j * 2048 + (SO)); \
    } \
    _Pragma("unroll") \
    for (int i = 0; i < 4; ++i) \
        af[i] = *(const short8*)(base_ + aoff + (MH) * 8192 + i * 2048 + (SO)); \
    STG; \
    __builtin_amdgcn_s_barrier(); \
    asm volatile("s_waitcnt lgkmcnt(0)" ::: "memory"); \
    __builtin_amdgcn_s_setprio(1); \
    _Pragma("unroll") \
    for (int i = 0; i < 4; ++i) \
        _Pragma("unroll") \
        for (int j = 0; j < 4; ++j) \
            acc[(MH) * 4 + i][j] = __builtin_amdgcn_mfma_f32_16x16x32_bf16( \
                af[i], bfr[j], acc[(MH) * 4 + i][j], 0, 0, 0); \
    __builtin_amdgcn_s_setprio(0); \
    VM; \
    __builtin_amdgcn_s_barrier(); \
} while (0)

    // one tile = 4 phases; stages: P1 qA0(t+1->OB), P2 qA1(t+1->OB),
    // P3 qB1(t+1->OB), P4 qB0(t+2->BUF) + vmcnt(2).
#define TILE(BUF, OB) do { \
    PHASE(BUF, 0, so0, true,  { STG_A(OB, 0, pA0); STG_A(OB, 1, pA1); }, VMNONE); \
    PHASE(BUF, 1, so0, false, { STG_A(OB, 2, pA2); STG_A(OB, 3, pA3); }, VMNONE); \
    PHASE(BUF, 0, so1, true,  { STG_B(OB, 2, pB2); STG_B(OB, 3, pB3); }, VMNONE); \
    PHASE(BUF, 1, so1, false, { STG_B(BUF, 0, pB0); STG_B(BUF, 1, pB1); }, VM2); \
} while (0)

    // prologue: tile0 full (8 gloads) into buf0 + tile1.qB0 (2) into buf1;
    // vmcnt(2) waits tile0's 8, leaves tile1.qB0 in flight (= loop steady state).
    STG_A(0, 0, pA0); STG_A(0, 1, pA1); STG_A(0, 2, pA2); STG_A(0, 3, pA3);
    STG_B(0, 0, pB0); STG_B(0, 1, pB1); STG_B(0, 2, pB2); STG_B(0, 3, pB3);
    STG_B(65536, 0, pB0); STG_B(65536, 1, pB1);
    asm volatile("s_waitcnt vmcnt(2)" ::: "memory");
    __builtin_amdgcn_s_barrier();

    // 160 tiles = 80 iterations x 2 (buf0 tile, buf1 tile).
    // Tail stages overrun K by <=2 tiles: reads land in the adjacent
    // workspace region, data never consumed.
#pragma unroll 1
    for (int it = 0; it < NTILE / 2; ++it) {
        TILE(0, 65536);
        TILE(65536, 0);
    }
    // drain in-flight LDS DMA before wave exit
    asm volatile("s_waitcnt vmcnt(0)" ::: "memory");

    // epilogue: raw fp32 partial; C/D layout: col = lane&15, row = quad*4 + reg
    float* Cz = Cp + (size_t)blockIdx.z * ((size_t)M_DIM * N_DIM);
#pragma unroll
    for (int i = 0; i < 8; ++i) {
        const int row = m0 + wm * 128 + i * 16 + quad * 4;
#pragma unroll
        for (int j = 0; j < 4; ++j) {
            const int col = n0 + wn * 64 + j * 16 + r16;
#pragma unroll
            for (int r = 0; r < 4; ++r)
                Cz[(size_t)(row + r) * N_DIM + col] = acc[i][j][r];
        }
    }
#undef TILE
#undef PHASE
#undef STG_A
#undef STG_B
#undef VM2
#undef VMNONE
}

// ---- 3. combine: out = tanh(C0 + C1 + bias), float4 vectorized ----
__global__ void combine_kernel(const float* __restrict__ Cp,
                               const float* __restrict__ bias,
                               float* __restrict__ out) {
    size_t t = (size_t)blockIdx.x * 256 + threadIdx.x;       // per float4
    const size_t stride = (size_t)M_DIM * N_DIM / 4;
    float4 a = ((const float4*)Cp)[t];
    float4 b = ((const float4*)Cp)[t + stride];
    float4 bv = ((const float4*)bias)[t & (N_DIM / 4 - 1)];
    float4 o;
    o.x = tanhf(a.x + b.x + bv.x);
    o.y = tanhf(a.y + b.y + bv.y);
    o.z = tanhf(a.z + b.z + bv.z);
    o.w = tanhf(a.w + b.w + bv.w);
    ((float4*)out)[t] = o;
}

extern "C" void kernel_launch(void* const* d_in, const int* in_sizes, int n_in,
                              void* d_out, int out_size, void* d_ws, size_t ws_size,
                              hipStream_t stream) {
    const float* x    = (const float*)d_in[0];
    const float* kv   = (const float*)d_in[1];
    const float* bias = (const float*)d_in[2];
    const int*   ind  = (const int*)d_in[3];
    int nnz = in_sizes[1];

    unsigned short* Wbt = (unsigned short*)d_ws;                        // bf16 W^T (N x KP)
    unsigned short* xb  = (unsigned short*)((char*)d_ws + XB_OFFSET);   // bf16 x (M x KP)
    float* Cp = (float*)((char*)d_ws + CP_OFFSET);                      // 2 x 33.55 MB partials

    // 1. cooperative prep: zero Wbt -> grid.sync -> scatter + convert
    {
        const float* xa = x; unsigned short* xba = xb;
        float4* wza = (float4*)Wbt;
        const float* kva = kv; const int* inda = ind;
        unsigned int* Wa = (unsigned int*)Wbt;
        void* args[] = { (void*)&xa, (void*)&xba, (void*)&wza,
                         (void*)&kva, (void*)&inda, (void*)&Wa, (void*)&nnz };
        hipLaunchCooperativeKernel((void*)prep_kernel, dim3(1024), dim3(256),
                                   args, 0, stream);
    }
    // 2. split-K=2 GEMM partials, 256x256 tiles, 1 WG/CU
    gemm256_kernel<<<dim3(N_DIM / 256, M_DIM / 256, 2), 512, 0, stream>>>(
        xb, Wbt, Cp);
    // 3. combine + bias + tanh
    combine_kernel<<<(M_DIM * N_DIM) / (256 * 4), 256, 0, stream>>>(
        Cp, bias, (float*)d_out);
}

// Round 10
// 613.930 us; speedup vs baseline: 1.4299x; 1.4299x over previous
//
#include <hip/hip_runtime.h>
#include <cstdint>
#include <cstddef>

#define M_DIM 2048
#define N_DIM 4096
#define K_DIM 20000
#define KP    20480                 /* K padded to multiple of 64 (zero-filled) */
#define KZ    10240                 /* K per split-K plane (2 planes) */
#define NTILE 160                   /* KZ / 64 K-tiles per plane */
#define WBT_BYTES  167772160UL      /* 4096*20480*2 : bf16 W^T (N x KP) */
#define XB_OFFSET  167772160UL      /* bf16 x (M x KP) after Wbt */
#define CP_OFFSET  251658240UL      /* 2x fp32 C-partials after xb */
#define BIN_OFFSET CP_OFFSET        /* binned COO records alias Cp (consumed before gemm writes Cp) */
#define CUR_OFFSET 318767104UL      /* bucket cursors after Cp region (16 KB) */
#define NBUCKET 256
#define BUCKET_CAP 16384            /* slots per bucket (mean 7812, +97 sigma) */
#define LDS_ECAP 9216               /* records cached in LDS (mean+16 sigma) */

typedef __attribute__((ext_vector_type(8))) short short8;
typedef __attribute__((ext_vector_type(4))) float float4v;
typedef __attribute__((ext_vector_type(8))) unsigned short ushort8;

__device__ __forceinline__ unsigned short f2bf_rne(float f) {
    union { float f; unsigned int u; } v; v.f = f;
    unsigned int u = v.u;
    u += 0x7FFFu + ((u >> 16) & 1u);   // round-to-nearest-even
    return (unsigned short)(u >> 16);
}

__device__ __forceinline__ void gload_lds16(const void* g, void* l) {
    __builtin_amdgcn_global_load_lds(
        (const __attribute__((address_space(1))) void*)g,
        (__attribute__((address_space(3))) void*)l, 16, 0, 0);
}

// ---- 1. bin: partition COO entries into 256 buckets of 16 columns ----
// 1024 blocks x 256 thr, ~1954 entries/block. LDS histogram; one global
// atomicAdd per (block,bucket) reserves a contiguous run (order within a
// bucket is irrelevant); records written to fixed-stride bucket regions.
// Record: .x = ((c&15)<<16)|r, .y = fp32 bits of v.
__global__ __launch_bounds__(256) void bin_kernel(
    const float* __restrict__ kv, const int* __restrict__ ind, int nnz,
    uint2* __restrict__ binned, unsigned int* __restrict__ cursor) {
    __shared__ unsigned int hist[NBUCKET];
    __shared__ unsigned int base[NBUCKET];
    __shared__ unsigned int run[NBUCKET];
    const int tid = threadIdx.x;
    const int per_block = (nnz + 1023) >> 10;
    const int start = blockIdx.x * per_block;
    const int limit = min(per_block, nnz - start);

    hist[tid] = 0u;
    __syncthreads();

    int bkt[8]; unsigned int meta[8]; float val[8];
    #pragma unroll
    for (int i = 0; i < 8; ++i) {
        int j = i * 256 + tid;
        bkt[i] = -1;
        if (j < limit) {
            int idx = start + j;
            int r = ind[2 * idx];      // input_dim index (K), < 20000
            int c = ind[2 * idx + 1];  // units index (N), < 4096
            val[i] = kv[idx];
            bkt[i] = c >> 4;
            meta[i] = ((unsigned int)(c & 15) << 16) | (unsigned int)r;
            atomicAdd(&hist[bkt[i]], 1u);
        }
    }
    __syncthreads();
    {
        unsigned int n = hist[tid];
        base[tid] = n ? atomicAdd(&cursor[tid * 16], n) : 0u;   // 64B-padded counters
        run[tid] = 0u;
    }
    __syncthreads();
    #pragma unroll
    for (int i = 0; i < 8; ++i) {
        if (bkt[i] >= 0) {
            unsigned int slot = base[bkt[i]] + atomicAdd(&run[bkt[i]], 1u);
            if (slot < BUCKET_CAP) {
                uint2 e; e.x = meta[i]; e.y = __float_as_uint(val[i]);
                binned[(size_t)bkt[i] * BUCKET_CAP + slot] = e;
            }
        }
    }
}

// ---- 2. accumulate: build 16 bf16 W^T columns per block, no global atomics ----
// 256 blocks x 512 thr, 152 KB LDS (row fp32 80KB + 9216 records 72KB).
// Per column: zero LDS row, scan bucket records (ds_add_f32 on match: exact
// fp32 duplicate accumulation, single bf16 rounding), stream row out
// coalesced (b128 LDS reads at 16B lane stride = conflict-free; 8B stores).
// Writes EVERY Wbt byte incl. K-pad -> no separate zero kernel needed.
__global__ __launch_bounds__(512) void accum_kernel(
    const uint2* __restrict__ binned, const unsigned int* __restrict__ cursor,
    unsigned short* __restrict__ Wbt) {
    __shared__ float row[KP];            // 81920 B
    __shared__ uint2 ent[LDS_ECAP];      // 73728 B
    const int b   = blockIdx.x;
    const int tid = threadIdx.x;
    const unsigned int count = min(cursor[b * 16], (unsigned int)BUCKET_CAP);
    const uint2* gsrc = binned + (size_t)b * BUCKET_CAP;

    for (unsigned int i = tid; i < count && i < LDS_ECAP; i += 512)
        ent[i] = gsrc[i];
    __syncthreads();

    for (int cc = 0; cc < 16; ++cc) {
        float4v* r4 = (float4v*)row;
        #pragma unroll
        for (int i = 0; i < 10; ++i)                  // 5120 float4 slots
            r4[tid + i * 512] = (float4v){0.f, 0.f, 0.f, 0.f};
        __syncthreads();
        for (unsigned int i = tid; i < count; i += 512) {
            uint2 e = (i < LDS_ECAP) ? ent[i] : gsrc[i];
            if ((int)(e.x >> 16) == cc)
                atomicAdd(&row[e.x & 0xFFFFu], __uint_as_float(e.y));
        }
        __syncthreads();
        unsigned short* dst = Wbt + (size_t)(b * 16 + cc) * KP;
        #pragma unroll
        for (int i = 0; i < 10; ++i) {                // 5120 chunks of 4
            int ch = tid + i * 512;
            float4v f = *(float4v*)&row[ch * 4];      // LDS b128, stride 16B
            ushort4 o;
            o.x = f2bf_rne(f[0]); o.y = f2bf_rne(f[1]);
            o.z = f2bf_rne(f[2]); o.w = f2bf_rne(f[3]);
            *(ushort4*)(dst + ch * 4) = o;            // 8B coalesced store
        }
        __syncthreads();
    }
}

// ---- 3. fp32 -> bf16 convert for x, writes K-pad zeros itself ----
__global__ void convert_kernel(const float* __restrict__ src,
                               unsigned short* __restrict__ dst) {
    size_t t = (size_t)blockIdx.x * 256 + threadIdx.x;
    int row = (int)(t / 2560);
    int c8  = (int)(t % 2560);
    ushort8 o;
    if (c8 < 2500) {
        const float4* sv = (const float4*)(src + (size_t)row * K_DIM + (size_t)c8 * 8);
        float4 a = sv[0];
        float4 b = sv[1];
        o[0] = f2bf_rne(a.x); o[1] = f2bf_rne(a.y);
        o[2] = f2bf_rne(a.z); o[3] = f2bf_rne(a.w);
        o[4] = f2bf_rne(b.x); o[5] = f2bf_rne(b.y);
        o[6] = f2bf_rne(b.z); o[7] = f2bf_rne(b.w);
    } else {
        o = (ushort8)0;
    }
    *(ushort8*)(dst + (size_t)row * KP + (size_t)c8 * 8) = o;
}

// ---- 4. 256x256-tile split-K=2 GEMM, 4-phase/tile schedule, XOR-swizzled LDS ----
// (round-4/6 kernel, verbatim: 281 us, MfmaUtil 52%, 0 bank conflicts)
__global__ __launch_bounds__(512, 2) void gemm256_kernel(
    const unsigned short* __restrict__ A,
    const unsigned short* __restrict__ Bt,
    float* __restrict__ Cp) {

    __shared__ unsigned short L[65536];    // 131072 B

    const int t    = threadIdx.x;
    const int w    = t >> 6;
    const int l    = t & 63;
    const int quad = l >> 4;
    const int r16  = l & 15;
    const int wm   = w >> 2;               // 0..1
    const int wn   = w & 3;                // 0..3

    const int m0 = blockIdx.y * 256;
    const int n0 = blockIdx.x * 256;
    const size_t k0 = (size_t)blockIdx.z * KZ;

    const int lr8 = l >> 3;
    const int sl  = (l & 7) ^ lr8;
    const int w1024 = w << 10;

    const unsigned short* pA0 = A  + (size_t)(m0 +   0 + w * 8 + lr8) * KP + k0 + sl * 8;
    const unsigned short* pA1 = A  + (size_t)(m0 +  64 + w * 8 + lr8) * KP + k0 + sl * 8;
    const unsigned short* pA2 = A  + (size_t)(m0 + 128 + w * 8 + lr8) * KP + k0 + sl * 8;
    const unsigned short* pA3 = A  + (size_t)(m0 + 192 + w * 8 + lr8) * KP + k0 + sl * 8;
    const unsigned short* pB0 = Bt + (size_t)(n0 +   0 + w * 8 + lr8) * KP + k0 + sl * 8;
    const unsigned short* pB1 = Bt + (size_t)(n0 +  64 + w * 8 + lr8) * KP + k0 + sl * 8;
    const unsigned short* pB2 = Bt + (size_t)(n0 + 128 + w * 8 + lr8) * KP + k0 + sl * 8;
    const unsigned short* pB3 = Bt + (size_t)(n0 + 192 + w * 8 + lr8) * KP + k0 + sl * 8;

    char* Lb = (char*)L;

#define STG_A(OB, Q, P) do { \
    gload_lds16(P, Lb + (OB) + (Q) * 8192 + w1024); P += 64; } while (0)
#define STG_B(OB, Q, P) do { \
    gload_lds16(P, Lb + (OB) + 32768 + (Q) * 8192 + w1024); P += 64; } while (0)

    const int h   = r16 & 7;
    const int so0 = ((quad ^ h) << 4);          // kh = 0
    const int so1 = (((4 | quad) ^ h) << 4);    // kh = 1
    const int aoff = wm * 16384 + r16 * 128;    // + mh*8192 + i*2048
    const int boff = 32768 + wn * 8192 + r16 * 128;   // + j*2048

    float4v acc[8][4];
#pragma unroll
    for (int i = 0; i < 8; ++i)
#pragma unroll
        for (int j = 0; j < 4; ++j)
            acc[i][j] = (float4v){0.f, 0.f, 0.f, 0.f};

    short8 bfr[4], af[4];

#define VM2 asm volatile("s_waitcnt vmcnt(2)" ::: "memory")
#define VMNONE ((void)0)

#define PHASE(BUF, MH, SO, LOADB, STG, VM) do { \
    const char* base_ = Lb + (BUF); \
    if (LOADB) { \
        _Pragma("unroll") \
        for (int j = 0; j < 4; ++j) \
            bfr[j] = *(const short8*)(base_ + boff + j * 2048 + (SO)); \
    } \
    _Pragma("unroll") \
    for (int i = 0; i < 4; ++i) \
        af[i] = *(const short8*)(base_ + aoff + (MH) * 8192 + i * 2048 + (SO)); \
    STG; \
    __builtin_amdgcn_s_barrier(); \
    asm volatile("s_waitcnt lgkmcnt(0)" ::: "memory"); \
    __builtin_amdgcn_s_setprio(1); \
    _Pragma("unroll") \
    for (int i = 0; i < 4; ++i) \
        _Pragma("unroll") \
        for (int j = 0; j < 4; ++j) \
            acc[(MH) * 4 + i][j] = __builtin_amdgcn_mfma_f32_16x16x32_bf16( \
                af[i], bfr[j], acc[(MH) * 4 + i][j], 0, 0, 0); \
    __builtin_amdgcn_s_setprio(0); \
    VM; \
    __builtin_amdgcn_s_barrier(); \
} while (0)

#define TILE(BUF, OB) do { \
    PHASE(BUF, 0, so0, true,  { STG_A(OB, 0, pA0); STG_A(OB, 1, pA1); }, VMNONE); \
    PHASE(BUF, 1, so0, false, { STG_A(OB, 2, pA2); STG_A(OB, 3, pA3); }, VMNONE); \
    PHASE(BUF, 0, so1, true,  { STG_B(OB, 2, pB2); STG_B(OB, 3, pB3); }, VMNONE); \
    PHASE(BUF, 1, so1, false, { STG_B(BUF, 0, pB0); STG_B(BUF, 1, pB1); }, VM2); \
} while (0)

    STG_A(0, 0, pA0); STG_A(0, 1, pA1); STG_A(0, 2, pA2); STG_A(0, 3, pA3);
    STG_B(0, 0, pB0); STG_B(0, 1, pB1); STG_B(0, 2, pB2); STG_B(0, 3, pB3);
    STG_B(65536, 0, pB0); STG_B(65536, 1, pB1);
    asm volatile("s_waitcnt vmcnt(2)" ::: "memory");
    __builtin_amdgcn_s_barrier();

#pragma unroll 1
    for (int it = 0; it < NTILE / 2; ++it) {
        TILE(0, 65536);
        TILE(65536, 0);
    }
    asm volatile("s_waitcnt vmcnt(0)" ::: "memory");

    float* Cz = Cp + (size_t)blockIdx.z * ((size_t)M_DIM * N_DIM);
#pragma unroll
    for (int i = 0; i < 8; ++i) {
        const int row = m0 + wm * 128 + i * 16 + quad * 4;
#pragma unroll
        for (int j = 0; j < 4; ++j) {
            const int col = n0 + wn * 64 + j * 16 + r16;
#pragma unroll
            for (int r = 0; r < 4; ++r)
                Cz[(size_t)(row + r) * N_DIM + col] = acc[i][j][r];
        }
    }
#undef TILE
#undef PHASE
#undef STG_A
#undef STG_B
#undef VM2
#undef VMNONE
}

// ---- 5. combine: out = tanh(C0 + C1 + bias), float4 vectorized ----
__global__ void combine_kernel(const float* __restrict__ Cp,
                               const float* __restrict__ bias,
                               float* __restrict__ out) {
    size_t t = (size_t)blockIdx.x * 256 + threadIdx.x;       // per float4
    const size_t stride = (size_t)M_DIM * N_DIM / 4;
    float4 a = ((const float4*)Cp)[t];
    float4 b = ((const float4*)Cp)[t + stride];
    float4 bv = ((const float4*)bias)[t & (N_DIM / 4 - 1)];
    float4 o;
    o.x = tanhf(a.x + b.x + bv.x);
    o.y = tanhf(a.y + b.y + bv.y);
    o.z = tanhf(a.z + b.z + bv.z);
    o.w = tanhf(a.w + b.w + bv.w);
    ((float4*)out)[t] = o;
}

extern "C" void kernel_launch(void* const* d_in, const int* in_sizes, int n_in,
                              void* d_out, int out_size, void* d_ws, size_t ws_size,
                              hipStream_t stream) {
    const float* x    = (const float*)d_in[0];
    const float* kv   = (const float*)d_in[1];
    const float* bias = (const float*)d_in[2];
    const int*   ind  = (const int*)d_in[3];
    const int nnz = in_sizes[1];

    unsigned short* Wbt = (unsigned short*)d_ws;                          // bf16 W^T (N x KP)
    unsigned short* xb  = (unsigned short*)((char*)d_ws + XB_OFFSET);     // bf16 x (M x KP)
    float* Cp           = (float*)((char*)d_ws + CP_OFFSET);              // 2 x 33.55 MB partials
    uint2* binned       = (uint2*)((char*)d_ws + BIN_OFFSET);             // 32 MB, aliases Cp
    unsigned int* cursor = (unsigned int*)((char*)d_ws + CUR_OFFSET);     // 256 x 64B

    // 1. zero bucket cursors (16 KB)
    hipMemsetAsync(cursor, 0, NBUCKET * 64, stream);
    // 2. bin COO entries into 256 x 16-column buckets (no data atomics)
    bin_kernel<<<1024, 256, 0, stream>>>(kv, ind, nnz, binned, cursor);
    // 3. accumulate buckets -> bf16 W^T via LDS fp32 rows (writes ALL of Wbt)
    accum_kernel<<<NBUCKET, 512, 0, stream>>>(binned, cursor, Wbt);
    // 4. x fp32 -> bf16 (writes its own K-pad zeros)
    convert_kernel<<<(M_DIM * (KP / 8)) / 256, 256, 0, stream>>>(x, xb);
    // 5. split-K=2 GEMM partials, 256x256 tiles, 1 WG/CU
    gemm256_kernel<<<dim3(N_DIM / 256, M_DIM / 256, 2), 512, 0, stream>>>(
        xb, Wbt, Cp);
    // 6. combine + bias + tanh
    combine_kernel<<<(M_DIM * N_DIM) / (256 * 4), 256, 0, stream>>>(
        Cp, bias, (float*)d_out);
}